// Round 6
// baseline (437.811 us; speedup 1.0000x reference)
//
#include <hip/hip_runtime.h>
#include <hip/hip_bf16.h>
#include <math.h>

#define N_NODES 200000
#define EMB_DIM 64
#define E_ADJ 1600000
#define E_TR 65536
#define NUM_NEG 16
#define EPS 1e-7f
#define MIN_NORM 1e-15f
#define MAX_SQDIST 50.0f
#define MARGIN 0.1f
#define LOSS_BLOCKS (E_TR / 4)   // 16384 blocks, 4 edges (waves) each

typedef float f4 __attribute__((ext_vector_type(4)));

__device__ __forceinline__ float group_reduce16(float v) {
    v += __shfl_xor(v, 8, 64);
    v += __shfl_xor(v, 4, 64);
    v += __shfl_xor(v, 2, 64);
    v += __shfl_xor(v, 1, 64);
    return v;
}

__device__ __forceinline__ float dot4(f4 a, f4 b) {
    return a.x * b.x + a.y * b.y + a.z * b.z + a.w * b.w;
}

// Kernel 0: pack (col<<4, val) -> int2 so the spmm inner loop does one dwordx2
// load per edge and a pure 32-bit gather index.
__global__ void pack_kernel(const int* __restrict__ cols, const float* __restrict__ vals,
                            int2* __restrict__ ev) {
    int i = blockIdx.x * blockDim.x + threadIdx.x;
    if (i < E_ADJ) {
        int c = __builtin_nontemporal_load(cols + i);
        float v = __builtin_nontemporal_load(vals + i);
        ev[i] = make_int2(c << 4, __float_as_int(v));
    }
}

// Kernel 1: row_ptr[r] = lower_bound(adj_row, r).
__global__ void rowptr_kernel(const int* __restrict__ rows, int* __restrict__ rp) {
    int r = blockIdx.x * blockDim.x + threadIdx.x;
    if (r > N_NODES) return;
    int lo = 0, hi = E_ADJ;
    while (lo < hi) {
        int mid = (lo + hi) >> 1;
        if (rows[mid] < r) lo = mid + 1; else hi = mid;
    }
    rp[r] = lo;
}

// Kernel 2: x_t = logmap0(weight). Wave handles 4 nodes; 16-lane group per node.
// weight is read once -> non-temporal, don't pollute LLC (x_t must stay resident).
__global__ void logmap0_kernel(const float* __restrict__ w, float* __restrict__ out) {
    int wave = (blockIdx.x * blockDim.x + threadIdx.x) >> 6;
    int lane = threadIdx.x & 63;
    int e = lane >> 4, d = lane & 15;
    int node = wave * 4 + e;
    if (node >= N_NODES) return;
    f4 v = __builtin_nontemporal_load(&((const f4*)w)[(node << 4) + d]);
    f4 y = v;
    if (d == 0) y.x = 0.0f;
    float n2 = group_reduce16(dot4(y, y));
    float ynorm = fmaxf(sqrtf(n2), MIN_NORM);
    float w0 = __shfl(v.x, lane & 48, 64);      // broadcast d==0 lane of group
    float theta = fmaxf(w0, 1.0f + EPS);
    float scale = acoshf(theta) / ynorm;
    ((f4*)out)[(node << 4) + d] = y * scale;
}

// Kernel 3: one SpMM layer. One wave per row; lane=16e+d; 4 edges per gather instr.
// Gather source + h_out stay cacheable (h_out is the next layer's gather source).
__global__ void spmm_kernel(const float* __restrict__ h_in, float* __restrict__ h_out,
                            const int2* __restrict__ ev, const int* __restrict__ rp) {
    int row = (blockIdx.x * blockDim.x + threadIdx.x) >> 6;
    int lane = threadIdx.x & 63;
    int e = lane >> 4, d = lane & 15;
    if (row >= N_NODES) return;
    int s = rp[row], eend = rp[row + 1];
    const f4* H = (const f4*)h_in;
    f4 acc = {0.f, 0.f, 0.f, 0.f};
    int i = s;
    for (; i + 8 <= eend; i += 8) {
        int2 cv0 = ev[i + e];
        int2 cv1 = ev[i + 4 + e];
        f4 g0 = H[cv0.x + d];
        f4 g1 = H[cv1.x + d];
        acc += g0 * __int_as_float(cv0.y);
        acc += g1 * __int_as_float(cv1.y);
    }
    if (i + 4 <= eend) {
        int2 cv = ev[i + e];
        f4 g = H[cv.x + d];
        acc += g * __int_as_float(cv.y);
        i += 4;
    }
    if (i + e < eend) {
        int2 cv = ev[i + e];
        f4 g = H[cv.x + d];
        acc += g * __int_as_float(cv.y);
    }
    // sum across the 4 edge-slot groups (same d, different e)
    acc.x += __shfl_xor(acc.x, 16, 64); acc.y += __shfl_xor(acc.y, 16, 64);
    acc.z += __shfl_xor(acc.z, 16, 64); acc.w += __shfl_xor(acc.w, 16, 64);
    acc.x += __shfl_xor(acc.x, 32, 64); acc.y += __shfl_xor(acc.y, 32, 64);
    acc.z += __shfl_xor(acc.z, 32, 64); acc.w += __shfl_xor(acc.w, 32, 64);
    if (e == 0)
        ((f4*)h_out)[(row << 4) + d] = acc;
}

// Kernel 4: fused layer-3 SpMM + (h1+h2+h3) + expmap0 + proj. Emits h and ||h||^2.
// h1/h2 streaming re-reads are read-once -> non-temporal (keep LLC for the
// h2 gather source). hfin/nrm2 stores stay cacheable (loss kernel gathers them).
__global__ void spmm_expmap_kernel(const float* __restrict__ h_gather,   // h2 (gather src)
                                   const float* __restrict__ h1, const float* __restrict__ h2,
                                   float* __restrict__ h, float* __restrict__ nrm2,
                                   const int2* __restrict__ ev, const int* __restrict__ rp) {
    int row = (blockIdx.x * blockDim.x + threadIdx.x) >> 6;
    int lane = threadIdx.x & 63;
    int e = lane >> 4, d = lane & 15;
    if (row >= N_NODES) return;
    int s = rp[row], eend = rp[row + 1];
    const f4* H = (const f4*)h_gather;
    f4 acc = {0.f, 0.f, 0.f, 0.f};
    int i = s;
    for (; i + 8 <= eend; i += 8) {
        int2 cv0 = ev[i + e];
        int2 cv1 = ev[i + 4 + e];
        f4 g0 = H[cv0.x + d];
        f4 g1 = H[cv1.x + d];
        acc += g0 * __int_as_float(cv0.y);
        acc += g1 * __int_as_float(cv1.y);
    }
    if (i + 4 <= eend) {
        int2 cv = ev[i + e];
        f4 g = H[cv.x + d];
        acc += g * __int_as_float(cv.y);
        i += 4;
    }
    if (i + e < eend) {
        int2 cv = ev[i + e];
        f4 g = H[cv.x + d];
        acc += g * __int_as_float(cv.y);
    }
    acc.x += __shfl_xor(acc.x, 16, 64); acc.y += __shfl_xor(acc.y, 16, 64);
    acc.z += __shfl_xor(acc.z, 16, 64); acc.w += __shfl_xor(acc.w, 16, 64);
    acc.x += __shfl_xor(acc.x, 32, 64); acc.y += __shfl_xor(acc.y, 32, 64);
    acc.z += __shfl_xor(acc.z, 32, 64); acc.w += __shfl_xor(acc.w, 32, 64);
    // acc (= h3 row) replicated on all 4 e-groups. Finish expmap on all lanes.
    int oi = (row << 4) + d;
    f4 a1 = __builtin_nontemporal_load(&((const f4*)h1)[oi]);
    f4 a2 = __builtin_nontemporal_load(&((const f4*)h2)[oi]);
    f4 u = (a1 + a2) + acc;                 // match ref accumulate order
    f4 x = u;
    if (d == 0) x.x = 0.0f;
    float n2 = group_reduce16(dot4(x, x));
    float xn = fmaxf(sqrtf(n2), MIN_NORM);
    float sh = sinhf(xn);
    f4 rest = x * (sh / xn);
    float r2 = group_reduce16(dot4(rest, rest));
    float first = sqrtf(1.0f + r2);
    f4 ov = rest;
    if (d == 0) ov.x = first;
    if (e == 0) {
        ((f4*)h)[oi] = ov;
        if (d == 0) nrm2[row] = first * first + r2;
    }
}

// Kernel 5: triplet loss + hard-negative mining. One wave per edge; lane=16e+d.
__global__ void loss_kernel(const float* __restrict__ h, const float* __restrict__ nrm2,
                            const int* __restrict__ anchor, const int* __restrict__ pos,
                            const int* __restrict__ neg, float* __restrict__ partials) {
    int wib = threadIdx.x >> 6;
    int lane = threadIdx.x & 63;
    int e = lane >> 4, d = lane & 15;
    int i = blockIdx.x * 4 + wib;
    const f4* H = (const f4*)h;

    int ia = anchor[i], ip = pos[i];
    f4 a4 = H[(ia << 4) + d];
    f4 p4 = H[(ip << 4) + d];
    const int* nrow = neg + (size_t)i * NUM_NEG;

    // value b handled by this group: neg index j = b*4 + e
    int   nb[4];
    float s[4];
    #pragma unroll
    for (int b = 0; b < 4; ++b) {
        nb[b] = nrow[b * 4 + e];
        f4 n4 = H[(nb[b] << 4) + d];
        s[b] = dot4(p4, n4);
    }
    float dap = dot4(a4, p4);

    // reduce-scatter the 4 values across the 16-lane group
    {
        bool hi = (d & 8) != 0;
        float send0 = hi ? s[0] : s[2];
        float send1 = hi ? s[1] : s[3];
        float r0 = __shfl_xor(send0, 8, 64);
        float r1 = __shfl_xor(send1, 8, 64);
        float k0 = hi ? s[2] : s[0];
        float k1 = hi ? s[3] : s[1];
        s[0] = k0 + r0;
        s[1] = k1 + r1;
    }
    float sv;
    {
        bool hi = (d & 4) != 0;
        float send = hi ? s[0] : s[1];
        float r = __shfl_xor(send, 4, 64);
        float k = hi ? s[1] : s[0];
        sv = k + r;
    }
    sv += __shfl_xor(sv, 2, 64);
    sv += __shfl_xor(sv, 1, 64);
    // lane (e,d) holds full <p, n_j> for j = b*4+e, b = ((d>>3)&1)*2 + ((d>>2)&1)
    int nidx_lane = (d & 8) ? ((d & 4) ? nb[3] : nb[2])
                            : ((d & 4) ? nb[1] : nb[0]);
    int j_lane = (((d >> 3) & 1) * 2 + ((d >> 2) & 1)) * 4 + e;

    float np2 = nrm2[ip];
    float bd = nrm2[nidx_lane] + np2 - 2.0f * sv;
    int bj = j_lane;
    // wave-wide argmin, first-occurrence tie-break (ties are duplicate nodes ->
    // bitwise-identical d2, so smaller-j rule matches jnp.argmin exactly)
    #pragma unroll
    for (int off = 32; off > 0; off >>= 1) {
        float od = __shfl_xor(bd, off, 64);
        int   oj = __shfl_xor(bj, off, 64);
        if (od < bd || (od == bd && oj < bj)) { bd = od; bj = oj; }
    }
    int bn = nrow[bj];                                  // uniform broadcast load
    f4 w4 = H[(bn << 4) + d];
    float dan = group_reduce16(dot4(a4, w4));
    dap = group_reduce16(dap);

    float loss = 0.0f;
    if (lane == 0) {
        float a0 = a4.x, p0 = p4.x, n0 = w4.x;
        float mink = dap - 2.0f * a0 * p0;
        float th = fmaxf(-mink, 1.0f + EPS);
        float ac = acoshf(th);
        float pos_score = fminf(ac * ac, MAX_SQDIST);
        float score = (1.0f - mink - a0 - p0) / (a0 * p0);
        float wgt = 1.0f / (1.0f + expf(score));        // sigmoid(-score)
        float minkn = dan - 2.0f * a0 * n0;
        float thn = fmaxf(-minkn, 1.0f + EPS);
        float acn = acoshf(thn);
        float neg_score = fminf(acn * acn, MAX_SQDIST);
        loss = fmaxf(pos_score - neg_score + MARGIN * wgt, 0.0f);
    }
    __shared__ float part[4];
    if (lane == 0) part[wib] = loss;
    __syncthreads();
    if (threadIdx.x == 0)
        __builtin_nontemporal_store(part[0] + part[1] + part[2] + part[3],
                                    partials + blockIdx.x);
}

// Kernel 6: sum the per-block partials. Single block, 1024 threads.
__global__ void reduce_kernel(const float* __restrict__ partials, float* __restrict__ out) {
    int tid = threadIdx.x;
    float s = 0.0f;
    for (int i = tid; i < LOSS_BLOCKS; i += 1024)
        s += __builtin_nontemporal_load(partials + i);
    #pragma unroll
    for (int off = 32; off > 0; off >>= 1)
        s += __shfl_xor(s, off, 64);
    __shared__ float part[16];
    if ((tid & 63) == 0) part[tid >> 6] = s;
    __syncthreads();
    if (tid == 0) {
        float t = 0.0f;
        #pragma unroll
        for (int k = 0; k < 16; ++k) t += part[k];
        out[0] = t;
    }
}

extern "C" void kernel_launch(void* const* d_in, const int* in_sizes, int n_in,
                              void* d_out, int out_size, void* d_ws, size_t ws_size,
                              hipStream_t stream) {
    const float* weight   = (const float*)d_in[0];
    const float* adj_vals = (const float*)d_in[1];
    const int*   adj_row  = (const int*)d_in[2];
    const int*   adj_col  = (const int*)d_in[3];
    const int*   anchor   = (const int*)d_in[4];
    const int*   pos      = (const int*)d_in[5];
    const int*   neg      = (const int*)d_in[6];
    float* out = (float*)d_out;

    const size_t NODE_BYTES = (size_t)N_NODES * EMB_DIM * sizeof(float); // 51.2 MB
    const size_t MB = 1024 * 1024;
    char* ws = (char*)d_ws;
    float* buf0 = (float*)(ws);                    // x_t, later reused as final h
    float* buf1 = (float*)(ws + NODE_BYTES);       // h1
    float* buf2 = (float*)(ws + 2 * NODE_BYTES);   // h2
    int*   rp   = (int*)  (ws + 3 * NODE_BYTES);             // row_ptr  (800 KB)
    float* nrm2 = (float*)(ws + 3 * NODE_BYTES + 1 * MB);    // ||h||^2  (800 KB)
    int2*  ev   = (int2*) (ws + 3 * NODE_BYTES + 2 * MB);    // packed edges (12.8 MB)
    float* partials = (float*)(ws + 3 * NODE_BYTES + 16 * MB); // 64 KB
    float* hfin = buf0;                            // buf0 dead after spmm layer 1

    int nblk_row   = (N_NODES + 3) / 4;      // wave per row, 4 waves/block
    int nblk_node4 = (N_NODES / 4 + 3) / 4;  // wave per 4 nodes

    pack_kernel<<<(E_ADJ + 255) / 256, 256, 0, stream>>>(adj_col, adj_vals, ev);
    rowptr_kernel<<<(N_NODES + 1 + 255) / 256, 256, 0, stream>>>(adj_row, rp);
    logmap0_kernel<<<nblk_node4, 256, 0, stream>>>(weight, buf0);
    spmm_kernel<<<nblk_row, 256, 0, stream>>>(buf0, buf1, ev, rp);
    spmm_kernel<<<nblk_row, 256, 0, stream>>>(buf1, buf2, ev, rp);
    spmm_expmap_kernel<<<nblk_row, 256, 0, stream>>>(buf2, buf1, buf2, hfin, nrm2, ev, rp);
    loss_kernel<<<LOSS_BLOCKS, 256, 0, stream>>>(hfin, nrm2, anchor, pos, neg, partials);
    reduce_kernel<<<1, 1024, 0, stream>>>(partials, out);
}

// Round 7
// 402.328 us; speedup vs baseline: 1.0882x; 1.0882x over previous
//
#include <hip/hip_runtime.h>
#include <hip/hip_bf16.h>
#include <math.h>

#define N_NODES 200000
#define EMB_DIM 64
#define E_ADJ 1600000
#define E_TR 65536
#define NUM_NEG 16
#define EPS 1e-7f
#define MIN_NORM 1e-15f
#define MAX_SQDIST 50.0f
#define MARGIN 0.1f
#define LOSS_BLOCKS (E_TR / 4)   // 16384 blocks, 4 edges (waves) each

typedef float f4 __attribute__((ext_vector_type(4)));

__device__ __forceinline__ float group_reduce16(float v) {
    v += __shfl_xor(v, 8, 64);
    v += __shfl_xor(v, 4, 64);
    v += __shfl_xor(v, 2, 64);
    v += __shfl_xor(v, 1, 64);
    return v;
}

__device__ __forceinline__ float dot4(f4 a, f4 b) {
    return a.x * b.x + a.y * b.y + a.z * b.z + a.w * b.w;
}

// ---- bf16 pack/unpack (RNE, unbiased) ----
__device__ __forceinline__ unsigned bfr(float f) {
    unsigned u = __float_as_uint(f);
    return (u + 0x7fffu + ((u >> 16) & 1u)) >> 16;
}
__device__ __forceinline__ uint2 f42bf(f4 v) {
    return make_uint2(bfr(v.x) | (bfr(v.y) << 16), bfr(v.z) | (bfr(v.w) << 16));
}
__device__ __forceinline__ f4 bf2f4(uint2 g) {
    f4 r;
    r.x = __uint_as_float(g.x << 16);
    r.y = __uint_as_float(g.x & 0xffff0000u);
    r.z = __uint_as_float(g.y << 16);
    r.w = __uint_as_float(g.y & 0xffff0000u);
    return r;
}

// Kernel 0: pack (col<<4, val) -> int2: one dwordx2 per edge, 32-bit gather index.
__global__ void pack_kernel(const int* __restrict__ cols, const float* __restrict__ vals,
                            int2* __restrict__ ev) {
    int i = blockIdx.x * blockDim.x + threadIdx.x;
    if (i < E_ADJ) ev[i] = make_int2(cols[i] << 4, __float_as_int(vals[i]));
}

// Kernel 1: row_ptr[r] = lower_bound(adj_row, r).
__global__ void rowptr_kernel(const int* __restrict__ rows, int* __restrict__ rp) {
    int r = blockIdx.x * blockDim.x + threadIdx.x;
    if (r > N_NODES) return;
    int lo = 0, hi = E_ADJ;
    while (lo < hi) {
        int mid = (lo + hi) >> 1;
        if (rows[mid] < r) lo = mid + 1; else hi = mid;
    }
    rp[r] = lo;
}

// Kernel 2: x_t = logmap0(weight) -> bf16. Wave = 4 nodes; 16-lane group per node.
__global__ void logmap0_kernel(const float* __restrict__ w, uint2* __restrict__ out) {
    int wave = (blockIdx.x * blockDim.x + threadIdx.x) >> 6;
    int lane = threadIdx.x & 63;
    int e = lane >> 4, d = lane & 15;
    int node = wave * 4 + e;
    if (node >= N_NODES) return;
    f4 v = ((const f4*)w)[(node << 4) + d];
    f4 y = v;
    if (d == 0) y.x = 0.0f;
    float n2 = group_reduce16(dot4(y, y));
    float ynorm = fmaxf(sqrtf(n2), MIN_NORM);
    float w0 = __shfl(v.x, lane & 48, 64);      // broadcast d==0 lane of group
    float theta = fmaxf(w0, 1.0f + EPS);
    float scale = acoshf(theta) / ynorm;
    out[(node << 4) + d] = f42bf(y * scale);
}

// Kernel 3: one SpMM layer, bf16 in / bf16 out (fp32 accumulate).
// One wave per row; lane=16e+d; one 128B line per edge-row gather.
__global__ void spmm_kernel(const uint2* __restrict__ h_in, uint2* __restrict__ h_out,
                            const int2* __restrict__ ev, const int* __restrict__ rp) {
    int row = (blockIdx.x * blockDim.x + threadIdx.x) >> 6;
    int lane = threadIdx.x & 63;
    int e = lane >> 4, d = lane & 15;
    if (row >= N_NODES) return;
    int s = rp[row], eend = rp[row + 1];
    f4 acc = {0.f, 0.f, 0.f, 0.f};
    int i = s;
    for (; i + 8 <= eend; i += 8) {
        int2 cv0 = ev[i + e];
        int2 cv1 = ev[i + 4 + e];
        uint2 g0 = h_in[cv0.x + d];
        uint2 g1 = h_in[cv1.x + d];
        acc += bf2f4(g0) * __int_as_float(cv0.y);
        acc += bf2f4(g1) * __int_as_float(cv1.y);
    }
    if (i + 4 <= eend) {
        int2 cv = ev[i + e];
        uint2 g = h_in[cv.x + d];
        acc += bf2f4(g) * __int_as_float(cv.y);
        i += 4;
    }
    if (i + e < eend) {
        int2 cv = ev[i + e];
        uint2 g = h_in[cv.x + d];
        acc += bf2f4(g) * __int_as_float(cv.y);
    }
    // sum across the 4 edge-slot groups (same d, different e)
    acc.x += __shfl_xor(acc.x, 16, 64); acc.y += __shfl_xor(acc.y, 16, 64);
    acc.z += __shfl_xor(acc.z, 16, 64); acc.w += __shfl_xor(acc.w, 16, 64);
    acc.x += __shfl_xor(acc.x, 32, 64); acc.y += __shfl_xor(acc.y, 32, 64);
    acc.z += __shfl_xor(acc.z, 32, 64); acc.w += __shfl_xor(acc.w, 32, 64);
    if (e == 0)
        h_out[(row << 4) + d] = f42bf(acc);
}

// Kernel 4: fused layer-3 SpMM + (h1+h2+h3) + expmap0 + proj.
// Gathers bf16 h2; streams bf16 h1/h2; emits fp32 h and ||h||^2.
__global__ void spmm_expmap_kernel(const uint2* __restrict__ h_gather,   // h2 bf16
                                   const uint2* __restrict__ h1, const uint2* __restrict__ h2,
                                   float* __restrict__ h, float* __restrict__ nrm2,
                                   const int2* __restrict__ ev, const int* __restrict__ rp) {
    int row = (blockIdx.x * blockDim.x + threadIdx.x) >> 6;
    int lane = threadIdx.x & 63;
    int e = lane >> 4, d = lane & 15;
    if (row >= N_NODES) return;
    int s = rp[row], eend = rp[row + 1];
    f4 acc = {0.f, 0.f, 0.f, 0.f};
    int i = s;
    for (; i + 8 <= eend; i += 8) {
        int2 cv0 = ev[i + e];
        int2 cv1 = ev[i + 4 + e];
        uint2 g0 = h_gather[cv0.x + d];
        uint2 g1 = h_gather[cv1.x + d];
        acc += bf2f4(g0) * __int_as_float(cv0.y);
        acc += bf2f4(g1) * __int_as_float(cv1.y);
    }
    if (i + 4 <= eend) {
        int2 cv = ev[i + e];
        uint2 g = h_gather[cv.x + d];
        acc += bf2f4(g) * __int_as_float(cv.y);
        i += 4;
    }
    if (i + e < eend) {
        int2 cv = ev[i + e];
        uint2 g = h_gather[cv.x + d];
        acc += bf2f4(g) * __int_as_float(cv.y);
    }
    acc.x += __shfl_xor(acc.x, 16, 64); acc.y += __shfl_xor(acc.y, 16, 64);
    acc.z += __shfl_xor(acc.z, 16, 64); acc.w += __shfl_xor(acc.w, 16, 64);
    acc.x += __shfl_xor(acc.x, 32, 64); acc.y += __shfl_xor(acc.y, 32, 64);
    acc.z += __shfl_xor(acc.z, 32, 64); acc.w += __shfl_xor(acc.w, 32, 64);
    // acc (= h3 row) replicated on all 4 e-groups. Finish expmap on all lanes.
    int oi = (row << 4) + d;
    f4 a1 = bf2f4(h1[oi]);
    f4 a2 = bf2f4(h2[oi]);
    f4 u = (a1 + a2) + acc;                 // match ref accumulate order
    f4 x = u;
    if (d == 0) x.x = 0.0f;
    float n2 = group_reduce16(dot4(x, x));
    float xn = fmaxf(sqrtf(n2), MIN_NORM);
    float sh = sinhf(xn);
    f4 rest = x * (sh / xn);
    float r2 = group_reduce16(dot4(rest, rest));
    float first = sqrtf(1.0f + r2);
    f4 ov = rest;
    if (d == 0) ov.x = first;
    if (e == 0) {
        ((f4*)h)[oi] = ov;
        if (d == 0) nrm2[row] = first * first + r2;
    }
}

// Kernel 5: triplet loss + hard-negative mining. One wave per edge; lane=16e+d.
__global__ void loss_kernel(const float* __restrict__ h, const float* __restrict__ nrm2,
                            const int* __restrict__ anchor, const int* __restrict__ pos,
                            const int* __restrict__ neg, float* __restrict__ partials) {
    int wib = threadIdx.x >> 6;
    int lane = threadIdx.x & 63;
    int e = lane >> 4, d = lane & 15;
    int i = blockIdx.x * 4 + wib;
    const f4* H = (const f4*)h;

    int ia = anchor[i], ip = pos[i];
    f4 a4 = H[(ia << 4) + d];
    f4 p4 = H[(ip << 4) + d];
    const int* nrow = neg + (size_t)i * NUM_NEG;

    // value b handled by this group: neg index j = b*4 + e
    int   nb[4];
    float s[4];
    #pragma unroll
    for (int b = 0; b < 4; ++b) {
        nb[b] = nrow[b * 4 + e];
        f4 n4 = H[(nb[b] << 4) + d];
        s[b] = dot4(p4, n4);
    }
    float dap = dot4(a4, p4);

    // reduce-scatter the 4 values across the 16-lane group
    {
        bool hi = (d & 8) != 0;
        float send0 = hi ? s[0] : s[2];
        float send1 = hi ? s[1] : s[3];
        float r0 = __shfl_xor(send0, 8, 64);
        float r1 = __shfl_xor(send1, 8, 64);
        float k0 = hi ? s[2] : s[0];
        float k1 = hi ? s[3] : s[1];
        s[0] = k0 + r0;
        s[1] = k1 + r1;
    }
    float sv;
    {
        bool hi = (d & 4) != 0;
        float send = hi ? s[0] : s[1];
        float r = __shfl_xor(send, 4, 64);
        float k = hi ? s[1] : s[0];
        sv = k + r;
    }
    sv += __shfl_xor(sv, 2, 64);
    sv += __shfl_xor(sv, 1, 64);
    // lane (e,d) holds full <p, n_j> for j = b*4+e, b = ((d>>3)&1)*2 + ((d>>2)&1)
    int nidx_lane = (d & 8) ? ((d & 4) ? nb[3] : nb[2])
                            : ((d & 4) ? nb[1] : nb[0]);
    int j_lane = (((d >> 3) & 1) * 2 + ((d >> 2) & 1)) * 4 + e;

    float np2 = nrm2[ip];
    float bd = nrm2[nidx_lane] + np2 - 2.0f * sv;
    int bj = j_lane;
    // wave-wide argmin, first-occurrence tie-break (ties are duplicate nodes ->
    // bitwise-identical d2, so smaller-j rule matches jnp.argmin exactly)
    #pragma unroll
    for (int off = 32; off > 0; off >>= 1) {
        float od = __shfl_xor(bd, off, 64);
        int   oj = __shfl_xor(bj, off, 64);
        if (od < bd || (od == bd && oj < bj)) { bd = od; bj = oj; }
    }
    int bn = nrow[bj];                                  // uniform broadcast load
    f4 w4 = H[(bn << 4) + d];
    float dan = group_reduce16(dot4(a4, w4));
    dap = group_reduce16(dap);

    float loss = 0.0f;
    if (lane == 0) {
        float a0 = a4.x, p0 = p4.x, n0 = w4.x;
        float mink = dap - 2.0f * a0 * p0;
        float th = fmaxf(-mink, 1.0f + EPS);
        float ac = acoshf(th);
        float pos_score = fminf(ac * ac, MAX_SQDIST);
        float score = (1.0f - mink - a0 - p0) / (a0 * p0);
        float wgt = 1.0f / (1.0f + expf(score));        // sigmoid(-score)
        float minkn = dan - 2.0f * a0 * n0;
        float thn = fmaxf(-minkn, 1.0f + EPS);
        float acn = acoshf(thn);
        float neg_score = fminf(acn * acn, MAX_SQDIST);
        loss = fmaxf(pos_score - neg_score + MARGIN * wgt, 0.0f);
    }
    __shared__ float part[4];
    if (lane == 0) part[wib] = loss;
    __syncthreads();
    if (threadIdx.x == 0)
        partials[blockIdx.x] = part[0] + part[1] + part[2] + part[3];
}

// Kernel 6: sum the per-block partials. Single block, 1024 threads.
__global__ void reduce_kernel(const float* __restrict__ partials, float* __restrict__ out) {
    int tid = threadIdx.x;
    float s = 0.0f;
    for (int i = tid; i < LOSS_BLOCKS; i += 1024)
        s += partials[i];
    #pragma unroll
    for (int off = 32; off > 0; off >>= 1)
        s += __shfl_xor(s, off, 64);
    __shared__ float part[16];
    if ((tid & 63) == 0) part[tid >> 6] = s;
    __syncthreads();
    if (tid == 0) {
        float t = 0.0f;
        #pragma unroll
        for (int k = 0; k < 16; ++k) t += part[k];
        out[0] = t;
    }
}

extern "C" void kernel_launch(void* const* d_in, const int* in_sizes, int n_in,
                              void* d_out, int out_size, void* d_ws, size_t ws_size,
                              hipStream_t stream) {
    const float* weight   = (const float*)d_in[0];
    const float* adj_vals = (const float*)d_in[1];
    const int*   adj_row  = (const int*)d_in[2];
    const int*   adj_col  = (const int*)d_in[3];
    const int*   anchor   = (const int*)d_in[4];
    const int*   pos      = (const int*)d_in[5];
    const int*   neg      = (const int*)d_in[6];
    float* out = (float*)d_out;

    const size_t NODEF32 = (size_t)N_NODES * EMB_DIM * sizeof(float);           // 51.2 MB
    const size_t NODEBF  = (size_t)N_NODES * EMB_DIM * sizeof(unsigned short);  // 25.6 MB
    const size_t MB = 1024 * 1024;
    char* ws = (char*)d_ws;
    float* hfin = (float*)(ws);                        // final h (fp32)
    uint2* bf0  = (uint2*)(ws + NODEF32);              // x_t bf16, reused for h3? (no - dead after L1)
    uint2* bf1  = (uint2*)(ws + NODEF32 + NODEBF);     // h1 bf16
    uint2* bf2  = (uint2*)(ws + NODEF32 + 2 * NODEBF); // h2 bf16
    int*   rp   = (int*)  (ws + NODEF32 + 3 * NODEBF);            // row_ptr (800 KB)
    float* nrm2 = (float*)(ws + NODEF32 + 3 * NODEBF + 1 * MB);   // ||h||^2 (800 KB)
    int2*  ev   = (int2*) (ws + NODEF32 + 3 * NODEBF + 2 * MB);   // packed edges (12.8 MB)
    float* partials = (float*)(ws + NODEF32 + 3 * NODEBF + 16 * MB); // 64 KB

    int nblk_row   = (N_NODES + 3) / 4;      // wave per row, 4 waves/block
    int nblk_node4 = (N_NODES / 4 + 3) / 4;  // wave per 4 nodes

    pack_kernel<<<(E_ADJ + 255) / 256, 256, 0, stream>>>(adj_col, adj_vals, ev);
    rowptr_kernel<<<(N_NODES + 1 + 255) / 256, 256, 0, stream>>>(adj_row, rp);
    logmap0_kernel<<<nblk_node4, 256, 0, stream>>>(weight, bf0);
    spmm_kernel<<<nblk_row, 256, 0, stream>>>(bf0, bf1, ev, rp);
    spmm_kernel<<<nblk_row, 256, 0, stream>>>(bf1, bf2, ev, rp);
    spmm_expmap_kernel<<<nblk_row, 256, 0, stream>>>(bf2, bf1, bf2, hfin, nrm2, ev, rp);
    loss_kernel<<<LOSS_BLOCKS, 256, 0, stream>>>(hfin, nrm2, anchor, pos, neg, partials);
    reduce_kernel<<<1, 1024, 0, stream>>>(partials, out);
}

// Round 8
// 361.214 us; speedup vs baseline: 1.2121x; 1.1138x over previous
//
#include <hip/hip_runtime.h>
#include <hip/hip_bf16.h>
#include <math.h>

#define N_NODES 200000
#define EMB_DIM 64
#define E_ADJ 1600000
#define E_TR 65536
#define NUM_NEG 16
#define EPS 1e-7f
#define MIN_NORM 1e-15f
#define MAX_SQDIST 50.0f
#define MARGIN 0.1f
#define LOSS_BLOCKS (E_TR / 4)     // 16384 blocks, 4 edges (waves) each
#define SPMM_BLOCKS 2048           // persistent: 8 blocks/CU x 256 CU
#define NWAVES (SPMM_BLOCKS * 4)   // 8192 waves, ~25 rows each

#define PACK_BLOCKS ((E_ADJ + 255) / 256)        // 6250
#define RP_BLOCKS   ((N_NODES + 1 + 255) / 256)  // 782
#define LOG_BLOCKS  ((N_NODES + 15) / 16)        // 12500

typedef float f4 __attribute__((ext_vector_type(4)));

__device__ __forceinline__ float group_reduce16(float v) {
    v += __shfl_xor(v, 8, 64);
    v += __shfl_xor(v, 4, 64);
    v += __shfl_xor(v, 2, 64);
    v += __shfl_xor(v, 1, 64);
    return v;
}

__device__ __forceinline__ float dot4(f4 a, f4 b) {
    return a.x * b.x + a.y * b.y + a.z * b.z + a.w * b.w;
}

// ---- bf16 pack/unpack (RNE, unbiased) ----
__device__ __forceinline__ unsigned bfr(float f) {
    unsigned u = __float_as_uint(f);
    return (u + 0x7fffu + ((u >> 16) & 1u)) >> 16;
}
__device__ __forceinline__ uint2 f42bf(f4 v) {
    return make_uint2(bfr(v.x) | (bfr(v.y) << 16), bfr(v.z) | (bfr(v.w) << 16));
}
__device__ __forceinline__ f4 bf2f4(uint2 g) {
    f4 r;
    r.x = __uint_as_float(g.x << 16);
    r.y = __uint_as_float(g.x & 0xffff0000u);
    r.z = __uint_as_float(g.y << 16);
    r.w = __uint_as_float(g.y & 0xffff0000u);
    return r;
}

// Prelude: pack edges + row_ptr + logmap0, one dispatch (block-range split).
__global__ void prelude_kernel(const int* __restrict__ cols, const float* __restrict__ vals,
                               int2* __restrict__ ev, const int* __restrict__ rows,
                               int* __restrict__ rp, const float* __restrict__ w,
                               uint2* __restrict__ xt) {
    int b = blockIdx.x;
    if (b < PACK_BLOCKS) {
        int i = b * 256 + threadIdx.x;
        if (i < E_ADJ) ev[i] = make_int2(cols[i] << 4, __float_as_int(vals[i]));
    } else if (b < PACK_BLOCKS + RP_BLOCKS) {
        int r = (b - PACK_BLOCKS) * 256 + threadIdx.x;
        if (r <= N_NODES) {
            int lo = 0, hi = E_ADJ;
            while (lo < hi) {
                int mid = (lo + hi) >> 1;
                if (rows[mid] < r) lo = mid + 1; else hi = mid;
            }
            rp[r] = lo;
        }
    } else {
        int bb = b - PACK_BLOCKS - RP_BLOCKS;
        int wave = bb * 4 + (threadIdx.x >> 6);
        int lane = threadIdx.x & 63;
        int e = lane >> 4, d = lane & 15;
        int node = wave * 4 + e;
        if (node < N_NODES) {
            f4 v = ((const f4*)w)[(node << 4) + d];
            f4 y = v;
            if (d == 0) y.x = 0.0f;
            float n2 = group_reduce16(dot4(y, y));
            float ynorm = fmaxf(sqrtf(n2), MIN_NORM);
            float w0 = __shfl(v.x, lane & 48, 64);
            float theta = fmaxf(w0, 1.0f + EPS);
            float scale = acoshf(theta) / ynorm;
            xt[(node << 4) + d] = f42bf(y * scale);
        }
    }
}

// SpMM row body: bf16 gather, fp32 accumulate. s/eend are SGPR (scalar branches).
__device__ __forceinline__ f4 spmm_row(const uint2* __restrict__ h_in,
                                       const int2* __restrict__ ev,
                                       int s, int eend, int e, int d) {
    f4 acc = {0.f, 0.f, 0.f, 0.f};
    int i = s;
    for (; i + 8 <= eend; i += 8) {
        int2 cv0 = ev[i + e];
        int2 cv1 = ev[i + 4 + e];
        uint2 g0 = h_in[cv0.x + d];
        uint2 g1 = h_in[cv1.x + d];
        acc += bf2f4(g0) * __int_as_float(cv0.y);
        acc += bf2f4(g1) * __int_as_float(cv1.y);
    }
    if (i + 4 <= eend) {
        int2 cv = ev[i + e];
        uint2 g = h_in[cv.x + d];
        acc += bf2f4(g) * __int_as_float(cv.y);
        i += 4;
    }
    if (i + e < eend) {
        int2 cv = ev[i + e];
        uint2 g = h_in[cv.x + d];
        acc += bf2f4(g) * __int_as_float(cv.y);
    }
    // sum across the 4 edge-slot groups (same d, different e)
    acc.x += __shfl_xor(acc.x, 16, 64); acc.y += __shfl_xor(acc.y, 16, 64);
    acc.z += __shfl_xor(acc.z, 16, 64); acc.w += __shfl_xor(acc.w, 16, 64);
    acc.x += __shfl_xor(acc.x, 32, 64); acc.y += __shfl_xor(acc.y, 32, 64);
    acc.z += __shfl_xor(acc.z, 32, 64); acc.w += __shfl_xor(acc.w, 32, 64);
    return acc;
}

// Kernel: persistent SpMM layer. Scalar rp loads, next-row rp prefetch.
__global__ void spmm_kernel(const uint2* __restrict__ h_in, uint2* __restrict__ h_out,
                            const int2* __restrict__ ev, const int* __restrict__ rp) {
    int lane = threadIdx.x & 63;
    int e = lane >> 4, d = lane & 15;
    int wid = __builtin_amdgcn_readfirstlane(blockIdx.x * 4 + (threadIdx.x >> 6));
    int row = wid;
    if (row >= N_NODES) return;
    int s = rp[row], eend = rp[row + 1];           // s_load (row is SGPR)
    for (;;) {
        int nrow = row + NWAVES;
        int ns = 0, nend = 0;
        if (nrow < N_NODES) { ns = rp[nrow]; nend = rp[nrow + 1]; }  // prefetch, scalar
        f4 acc = spmm_row(h_in, ev, s, eend, e, d);
        if (e == 0)
            h_out[(row << 4) + d] = f42bf(acc);
        if (nrow >= N_NODES) break;
        row = nrow; s = ns; eend = nend;
    }
}

// Kernel: persistent fused layer-3 SpMM + (h1+h2+h3) + expmap0 + proj.
__global__ void spmm_expmap_kernel(const uint2* __restrict__ h_gather,  // h2 bf16
                                   const uint2* __restrict__ h1, const uint2* __restrict__ h2,
                                   float* __restrict__ h, float* __restrict__ nrm2,
                                   const int2* __restrict__ ev, const int* __restrict__ rp) {
    int lane = threadIdx.x & 63;
    int e = lane >> 4, d = lane & 15;
    int wid = __builtin_amdgcn_readfirstlane(blockIdx.x * 4 + (threadIdx.x >> 6));
    int row = wid;
    if (row >= N_NODES) return;
    int s = rp[row], eend = rp[row + 1];
    for (;;) {
        int nrow = row + NWAVES;
        int ns = 0, nend = 0;
        if (nrow < N_NODES) { ns = rp[nrow]; nend = rp[nrow + 1]; }
        int oi = (row << 4) + d;
        f4 a1 = bf2f4(h1[oi]);                     // issue early, overlaps gathers
        f4 a2 = bf2f4(h2[oi]);
        f4 acc = spmm_row(h_gather, ev, s, eend, e, d);
        f4 u = (a1 + a2) + acc;                    // match ref accumulate order
        f4 x = u;
        if (d == 0) x.x = 0.0f;
        float n2 = group_reduce16(dot4(x, x));
        float xn = fmaxf(sqrtf(n2), MIN_NORM);
        float sh = sinhf(xn);
        f4 rest = x * (sh / xn);
        float r2 = group_reduce16(dot4(rest, rest));
        float first = sqrtf(1.0f + r2);
        f4 ov = rest;
        if (d == 0) ov.x = first;
        if (e == 0) {
            ((f4*)h)[oi] = ov;
            if (d == 0) nrm2[row] = first * first + r2;
        }
        if (nrow >= N_NODES) break;
        row = nrow; s = ns; eend = nend;
    }
}

// Kernel: triplet loss + hard-negative mining. One wave per edge; lane=16e+d.
// anchor/pos scalarized; neg row via one int4 broadcast load per group.
__global__ void loss_kernel(const float* __restrict__ h, const float* __restrict__ nrm2,
                            const int* __restrict__ anchor, const int* __restrict__ pos,
                            const int* __restrict__ neg, float* __restrict__ partials) {
    int wib = threadIdx.x >> 6;
    int lane = threadIdx.x & 63;
    int e = lane >> 4, d = lane & 15;
    int i = __builtin_amdgcn_readfirstlane(blockIdx.x * 4 + wib);
    const f4* H = (const f4*)h;

    int ia = anchor[i], ip = pos[i];               // s_load
    f4 a4 = H[(ia << 4) + d];
    f4 p4 = H[(ip << 4) + d];
    int4 nb4 = ((const int4*)(neg + (size_t)i * NUM_NEG))[e];  // group e: j = 4e+b

    float s[4];
    s[0] = dot4(p4, H[(nb4.x << 4) + d]);
    s[1] = dot4(p4, H[(nb4.y << 4) + d]);
    s[2] = dot4(p4, H[(nb4.z << 4) + d]);
    s[3] = dot4(p4, H[(nb4.w << 4) + d]);
    float dap = dot4(a4, p4);

    // reduce-scatter the 4 values across the 16-lane group
    {
        bool hi = (d & 8) != 0;
        float send0 = hi ? s[0] : s[2];
        float send1 = hi ? s[1] : s[3];
        float r0 = __shfl_xor(send0, 8, 64);
        float r1 = __shfl_xor(send1, 8, 64);
        float k0 = hi ? s[2] : s[0];
        float k1 = hi ? s[3] : s[1];
        s[0] = k0 + r0;
        s[1] = k1 + r1;
    }
    float sv;
    {
        bool hi = (d & 4) != 0;
        float send = hi ? s[0] : s[1];
        float r = __shfl_xor(send, 4, 64);
        float k = hi ? s[1] : s[0];
        sv = k + r;
    }
    sv += __shfl_xor(sv, 2, 64);
    sv += __shfl_xor(sv, 1, 64);
    // lane (e,d) holds <p,n_j> for j = 4e + b, b = ((d>>3)&1)*2 + ((d>>2)&1)
    int b_lane = ((d >> 3) & 1) * 2 + ((d >> 2) & 1);
    int nidx_lane = (d & 8) ? ((d & 4) ? nb4.w : nb4.z)
                            : ((d & 4) ? nb4.y : nb4.x);
    int j_lane = 4 * e + b_lane;

    float np2 = nrm2[ip];
    float bd = nrm2[nidx_lane] + np2 - 2.0f * sv;
    int bj = j_lane;
    // wave-wide argmin, first-occurrence tie-break (ties are duplicate nodes ->
    // bitwise-identical d2, so smaller-j rule matches jnp.argmin exactly)
    #pragma unroll
    for (int off = 32; off > 0; off >>= 1) {
        float od = __shfl_xor(bd, off, 64);
        int   oj = __shfl_xor(bj, off, 64);
        if (od < bd || (od == bd && oj < bj)) { bd = od; bj = oj; }
    }
    int bn = neg[(size_t)i * NUM_NEG + __builtin_amdgcn_readfirstlane(bj)];  // s_load
    f4 w4 = H[(bn << 4) + d];
    float dan = group_reduce16(dot4(a4, w4));
    dap = group_reduce16(dap);

    float loss = 0.0f;
    if (lane == 0) {
        float a0 = a4.x, p0 = p4.x, n0 = w4.x;
        float mink = dap - 2.0f * a0 * p0;
        float th = fmaxf(-mink, 1.0f + EPS);
        float ac = acoshf(th);
        float pos_score = fminf(ac * ac, MAX_SQDIST);
        float score = (1.0f - mink - a0 - p0) / (a0 * p0);
        float wgt = 1.0f / (1.0f + expf(score));        // sigmoid(-score)
        float minkn = dan - 2.0f * a0 * n0;
        float thn = fmaxf(-minkn, 1.0f + EPS);
        float acn = acoshf(thn);
        float neg_score = fminf(acn * acn, MAX_SQDIST);
        loss = fmaxf(pos_score - neg_score + MARGIN * wgt, 0.0f);
    }
    __shared__ float part[4];
    if (lane == 0) part[wib] = loss;
    __syncthreads();
    if (threadIdx.x == 0)
        partials[blockIdx.x] = part[0] + part[1] + part[2] + part[3];
}

// Final reduce. Single block, 1024 threads.
__global__ void reduce_kernel(const float* __restrict__ partials, float* __restrict__ out) {
    int tid = threadIdx.x;
    float s = 0.0f;
    for (int i = tid; i < LOSS_BLOCKS; i += 1024)
        s += partials[i];
    #pragma unroll
    for (int off = 32; off > 0; off >>= 1)
        s += __shfl_xor(s, off, 64);
    __shared__ float part[16];
    if ((tid & 63) == 0) part[tid >> 6] = s;
    __syncthreads();
    if (tid == 0) {
        float t = 0.0f;
        #pragma unroll
        for (int k = 0; k < 16; ++k) t += part[k];
        out[0] = t;
    }
}

extern "C" void kernel_launch(void* const* d_in, const int* in_sizes, int n_in,
                              void* d_out, int out_size, void* d_ws, size_t ws_size,
                              hipStream_t stream) {
    const float* weight   = (const float*)d_in[0];
    const float* adj_vals = (const float*)d_in[1];
    const int*   adj_row  = (const int*)d_in[2];
    const int*   adj_col  = (const int*)d_in[3];
    const int*   anchor   = (const int*)d_in[4];
    const int*   pos      = (const int*)d_in[5];
    const int*   neg      = (const int*)d_in[6];
    float* out = (float*)d_out;

    const size_t NODEF32 = (size_t)N_NODES * EMB_DIM * sizeof(float);           // 51.2 MB
    const size_t NODEBF  = (size_t)N_NODES * EMB_DIM * sizeof(unsigned short);  // 25.6 MB
    const size_t MB = 1024 * 1024;
    char* ws = (char*)d_ws;
    float* hfin = (float*)(ws);                        // final h (fp32)
    uint2* bf0  = (uint2*)(ws + NODEF32);              // x_t bf16
    uint2* bf1  = (uint2*)(ws + NODEF32 + NODEBF);     // h1 bf16
    uint2* bf2  = (uint2*)(ws + NODEF32 + 2 * NODEBF); // h2 bf16
    int*   rp   = (int*)  (ws + NODEF32 + 3 * NODEBF);            // row_ptr (800 KB)
    float* nrm2 = (float*)(ws + NODEF32 + 3 * NODEBF + 1 * MB);   // ||h||^2 (800 KB)
    int2*  ev   = (int2*) (ws + NODEF32 + 3 * NODEBF + 2 * MB);   // packed edges (12.8 MB)
    float* partials = (float*)(ws + NODEF32 + 3 * NODEBF + 16 * MB); // 64 KB

    prelude_kernel<<<PACK_BLOCKS + RP_BLOCKS + LOG_BLOCKS, 256, 0, stream>>>(
        adj_col, adj_vals, ev, adj_row, rp, weight, bf0);
    spmm_kernel<<<SPMM_BLOCKS, 256, 0, stream>>>(bf0, bf1, ev, rp);
    spmm_kernel<<<SPMM_BLOCKS, 256, 0, stream>>>(bf1, bf2, ev, rp);
    spmm_expmap_kernel<<<SPMM_BLOCKS, 256, 0, stream>>>(bf2, bf1, bf2, hfin, nrm2, ev, rp);
    loss_kernel<<<LOSS_BLOCKS, 256, 0, stream>>>(hfin, nrm2, anchor, pos, neg, partials);
    reduce_kernel<<<1, 1024, 0, stream>>>(partials, out);
}

// Round 9
// 353.202 us; speedup vs baseline: 1.2395x; 1.0227x over previous
//
#include <hip/hip_runtime.h>
#include <hip/hip_bf16.h>
#include <math.h>

#define N_NODES 200000
#define EMB_DIM 64
#define E_ADJ 1600000
#define E_TR 65536
#define NUM_NEG 16
#define EPS 1e-7f
#define MIN_NORM 1e-15f
#define MAX_SQDIST 50.0f
#define MARGIN 0.1f
#define LOSS_BLOCKS (E_TR / 4)     // 16384 blocks, 4 edges (waves) each
#define SPMM_BLOCKS 2048           // persistent: 8 blocks/CU x 256 CU
#define NWAVES (SPMM_BLOCKS * 4)   // 8192 waves
#define RPW 25                     // ceil(N_NODES / NWAVES) rows per wave (contiguous)
#define LDS_CAP 512                // staged edges per wave; ~200 expected, global fallback past this

#define PACK_BLOCKS ((E_ADJ + 255) / 256)        // 6250
#define RP_BLOCKS   ((N_NODES + 1 + 255) / 256)  // 782
#define LOG_BLOCKS  ((N_NODES + 15) / 16)        // 12500

typedef float f4 __attribute__((ext_vector_type(4)));

__device__ __forceinline__ float group_reduce16(float v) {
    v += __shfl_xor(v, 8, 64);
    v += __shfl_xor(v, 4, 64);
    v += __shfl_xor(v, 2, 64);
    v += __shfl_xor(v, 1, 64);
    return v;
}

__device__ __forceinline__ float dot4(f4 a, f4 b) {
    return a.x * b.x + a.y * b.y + a.z * b.z + a.w * b.w;
}

// ---- bf16 pack/unpack (RNE, unbiased) ----
__device__ __forceinline__ unsigned bfr(float f) {
    unsigned u = __float_as_uint(f);
    return (u + 0x7fffu + ((u >> 16) & 1u)) >> 16;
}
__device__ __forceinline__ uint2 f42bf(f4 v) {
    return make_uint2(bfr(v.x) | (bfr(v.y) << 16), bfr(v.z) | (bfr(v.w) << 16));
}
__device__ __forceinline__ f4 bf2f4(uint2 g) {
    f4 r;
    r.x = __uint_as_float(g.x << 16);
    r.y = __uint_as_float(g.x & 0xffff0000u);
    r.z = __uint_as_float(g.y << 16);
    r.w = __uint_as_float(g.y & 0xffff0000u);
    return r;
}

// Prelude: pack edges + row_ptr + logmap0, one dispatch (block-range split).
__global__ void prelude_kernel(const int* __restrict__ cols, const float* __restrict__ vals,
                               int2* __restrict__ ev, const int* __restrict__ rows,
                               int* __restrict__ rp, const float* __restrict__ w,
                               uint2* __restrict__ xt) {
    int b = blockIdx.x;
    if (b < PACK_BLOCKS) {
        int i = b * 256 + threadIdx.x;
        if (i < E_ADJ) ev[i] = make_int2(cols[i] << 4, __float_as_int(vals[i]));
    } else if (b < PACK_BLOCKS + RP_BLOCKS) {
        int r = (b - PACK_BLOCKS) * 256 + threadIdx.x;
        if (r <= N_NODES) {
            int lo = 0, hi = E_ADJ;
            while (lo < hi) {
                int mid = (lo + hi) >> 1;
                if (rows[mid] < r) lo = mid + 1; else hi = mid;
            }
            rp[r] = lo;
        }
    } else {
        int bb = b - PACK_BLOCKS - RP_BLOCKS;
        int wave = bb * 4 + (threadIdx.x >> 6);
        int lane = threadIdx.x & 63;
        int e = lane >> 4, d = lane & 15;
        int node = wave * 4 + e;
        if (node < N_NODES) {
            f4 v = ((const f4*)w)[(node << 4) + d];
            f4 y = v;
            if (d == 0) y.x = 0.0f;
            float n2 = group_reduce16(dot4(y, y));
            float ynorm = fmaxf(sqrtf(n2), MIN_NORM);
            float w0 = __shfl(v.x, lane & 48, 64);
            float theta = fmaxf(w0, 1.0f + EPS);
            float scale = acoshf(theta) / ynorm;
            xt[(node << 4) + d] = f42bf(y * scale);
        }
    }
}

// SpMM row body: bf16 gather, fp32 accumulate. Edge (col,val) records come from
// the wave's LDS stage (uniform select; global fallback past `staged`).
// Window structure identical to R8 -> bitwise-identical accumulation order.
__device__ __forceinline__ f4 spmm_row_lds(const uint2* __restrict__ h_in,
                                           const int2* __restrict__ ev,
                                           const int2* L, int ebase, int staged,
                                           int s, int re, int e, int d) {
    f4 acc = {0.f, 0.f, 0.f, 0.f};
    int i = s;
    for (; i + 8 <= re; i += 8) {
        int2 cv0, cv1;
        if (i + 8 - ebase <= staged) {            // wave-uniform select
            cv0 = L[i - ebase + e];
            cv1 = L[i - ebase + 4 + e];
        } else {
            cv0 = ev[i + e];
            cv1 = ev[i + 4 + e];
        }
        uint2 g0 = h_in[cv0.x + d];
        uint2 g1 = h_in[cv1.x + d];
        acc += bf2f4(g0) * __int_as_float(cv0.y);
        acc += bf2f4(g1) * __int_as_float(cv1.y);
    }
    if (i + 4 <= re) {
        int2 cv;
        if (i + 4 - ebase <= staged) cv = L[i - ebase + e];
        else                         cv = ev[i + e];
        uint2 g = h_in[cv.x + d];
        acc += bf2f4(g) * __int_as_float(cv.y);
        i += 4;
    }
    if (i + e < re) {                             // divergent lane guard (as R8)
        int2 cv;
        if (re - ebase <= staged) cv = L[i - ebase + e];
        else                      cv = ev[i + e];
        uint2 g = h_in[cv.x + d];
        acc += bf2f4(g) * __int_as_float(cv.y);
    }
    // sum across the 4 edge-slot groups (same d, different e)
    acc.x += __shfl_xor(acc.x, 16, 64); acc.y += __shfl_xor(acc.y, 16, 64);
    acc.z += __shfl_xor(acc.z, 16, 64); acc.w += __shfl_xor(acc.w, 16, 64);
    acc.x += __shfl_xor(acc.x, 32, 64); acc.y += __shfl_xor(acc.y, 32, 64);
    acc.z += __shfl_xor(acc.z, 32, 64); acc.w += __shfl_xor(acc.w, 32, 64);
    return acc;
}

// Kernel: persistent SpMM layer. Wave owns RPW contiguous rows; stages its whole
// edge range into LDS upfront (8 coalesced 512B loads), then the inner loop has
// gathers as the ONLY outstanding vmem (addresses fed from LDS, no vmem chain).
__global__ __launch_bounds__(256) void spmm_kernel(const uint2* __restrict__ h_in,
                                                   uint2* __restrict__ h_out,
                                                   const int2* __restrict__ ev,
                                                   const int* __restrict__ rp) {
    __shared__ int2 evs[4][LDS_CAP];               // 16 KB/block, per-wave regions
    int wib = threadIdx.x >> 6;
    int lane = threadIdx.x & 63;
    int e = lane >> 4, d = lane & 15;
    int wid = __builtin_amdgcn_readfirstlane(blockIdx.x * 4 + wib);
    int r0 = wid * RPW;
    if (r0 >= N_NODES) return;                     // whole block exits together
    int r1 = min(r0 + RPW, N_NODES);
    int ebase = rp[r0];                            // s_load
    int etot  = rp[r1];
    int staged = min(etot - ebase, LDS_CAP);
    int2* L = evs[wib];
    for (int k = lane; k < staged; k += 64)        // coalesced bulk stage
        L[k] = ev[ebase + k];
    __syncthreads();                               // all 4 waves alive in live blocks

    int s = ebase;
    int re = rp[r0 + 1];
    for (int row = r0; row < r1; ++row) {
        int re_next = (row + 1 < r1) ? rp[row + 2] : 0;   // scalar prefetch
        f4 acc = spmm_row_lds(h_in, ev, L, ebase, staged, s, re, e, d);
        if (e == 0)
            h_out[(row << 4) + d] = f42bf(acc);
        s = re; re = re_next;
    }
}

// Kernel: persistent fused layer-3 SpMM + (h1+h2+h3) + expmap0 + proj.
__global__ __launch_bounds__(256) void spmm_expmap_kernel(const uint2* __restrict__ h_gather,
                                                          const uint2* __restrict__ h1,
                                                          const uint2* __restrict__ h2,
                                                          float* __restrict__ h,
                                                          float* __restrict__ nrm2,
                                                          const int2* __restrict__ ev,
                                                          const int* __restrict__ rp) {
    __shared__ int2 evs[4][LDS_CAP];
    int wib = threadIdx.x >> 6;
    int lane = threadIdx.x & 63;
    int e = lane >> 4, d = lane & 15;
    int wid = __builtin_amdgcn_readfirstlane(blockIdx.x * 4 + wib);
    int r0 = wid * RPW;
    if (r0 >= N_NODES) return;
    int r1 = min(r0 + RPW, N_NODES);
    int ebase = rp[r0];
    int etot  = rp[r1];
    int staged = min(etot - ebase, LDS_CAP);
    int2* L = evs[wib];
    for (int k = lane; k < staged; k += 64)
        L[k] = ev[ebase + k];
    __syncthreads();

    int s = ebase;
    int re = rp[r0 + 1];
    for (int row = r0; row < r1; ++row) {
        int re_next = (row + 1 < r1) ? rp[row + 2] : 0;
        int oi = (row << 4) + d;
        f4 a1 = bf2f4(h1[oi]);                     // issue early, overlaps gathers
        f4 a2 = bf2f4(h2[oi]);
        f4 acc = spmm_row_lds(h_gather, ev, L, ebase, staged, s, re, e, d);
        f4 u = (a1 + a2) + acc;                    // match ref accumulate order
        f4 x = u;
        if (d == 0) x.x = 0.0f;
        float n2 = group_reduce16(dot4(x, x));
        float xn = fmaxf(sqrtf(n2), MIN_NORM);
        float sh = sinhf(xn);
        f4 rest = x * (sh / xn);
        float r2 = group_reduce16(dot4(rest, rest));
        float first = sqrtf(1.0f + r2);
        f4 ov = rest;
        if (d == 0) ov.x = first;
        if (e == 0) {
            ((f4*)h)[oi] = ov;
            if (d == 0) nrm2[row] = first * first + r2;
        }
        s = re; re = re_next;
    }
}

// Kernel: triplet loss + hard-negative mining. One wave per edge; lane=16e+d.
__global__ void loss_kernel(const float* __restrict__ h, const float* __restrict__ nrm2,
                            const int* __restrict__ anchor, const int* __restrict__ pos,
                            const int* __restrict__ neg, float* __restrict__ partials) {
    int wib = threadIdx.x >> 6;
    int lane = threadIdx.x & 63;
    int e = lane >> 4, d = lane & 15;
    int i = __builtin_amdgcn_readfirstlane(blockIdx.x * 4 + wib);
    const f4* H = (const f4*)h;

    int ia = anchor[i], ip = pos[i];               // s_load
    f4 a4 = H[(ia << 4) + d];
    f4 p4 = H[(ip << 4) + d];
    int4 nb4 = ((const int4*)(neg + (size_t)i * NUM_NEG))[e];  // group e: j = 4e+b

    float s[4];
    s[0] = dot4(p4, H[(nb4.x << 4) + d]);
    s[1] = dot4(p4, H[(nb4.y << 4) + d]);
    s[2] = dot4(p4, H[(nb4.z << 4) + d]);
    s[3] = dot4(p4, H[(nb4.w << 4) + d]);
    float dap = dot4(a4, p4);

    // reduce-scatter the 4 values across the 16-lane group
    {
        bool hi = (d & 8) != 0;
        float send0 = hi ? s[0] : s[2];
        float send1 = hi ? s[1] : s[3];
        float r0 = __shfl_xor(send0, 8, 64);
        float r1 = __shfl_xor(send1, 8, 64);
        float k0 = hi ? s[2] : s[0];
        float k1 = hi ? s[3] : s[1];
        s[0] = k0 + r0;
        s[1] = k1 + r1;
    }
    float sv;
    {
        bool hi = (d & 4) != 0;
        float send = hi ? s[0] : s[1];
        float r = __shfl_xor(send, 4, 64);
        float k = hi ? s[1] : s[0];
        sv = k + r;
    }
    sv += __shfl_xor(sv, 2, 64);
    sv += __shfl_xor(sv, 1, 64);
    // lane (e,d) holds <p,n_j> for j = 4e + b, b = ((d>>3)&1)*2 + ((d>>2)&1)
    int b_lane = ((d >> 3) & 1) * 2 + ((d >> 2) & 1);
    int nidx_lane = (d & 8) ? ((d & 4) ? nb4.w : nb4.z)
                            : ((d & 4) ? nb4.y : nb4.x);
    int j_lane = 4 * e + b_lane;

    float np2 = nrm2[ip];
    float bd = nrm2[nidx_lane] + np2 - 2.0f * sv;
    int bj = j_lane;
    // wave-wide argmin, first-occurrence tie-break (ties are duplicate nodes ->
    // bitwise-identical d2, so smaller-j rule matches jnp.argmin exactly)
    #pragma unroll
    for (int off = 32; off > 0; off >>= 1) {
        float od = __shfl_xor(bd, off, 64);
        int   oj = __shfl_xor(bj, off, 64);
        if (od < bd || (od == bd && oj < bj)) { bd = od; bj = oj; }
    }
    int bn = neg[(size_t)i * NUM_NEG + __builtin_amdgcn_readfirstlane(bj)];  // s_load
    f4 w4 = H[(bn << 4) + d];
    float dan = group_reduce16(dot4(a4, w4));
    dap = group_reduce16(dap);

    float loss = 0.0f;
    if (lane == 0) {
        float a0 = a4.x, p0 = p4.x, n0 = w4.x;
        float mink = dap - 2.0f * a0 * p0;
        float th = fmaxf(-mink, 1.0f + EPS);
        float ac = acoshf(th);
        float pos_score = fminf(ac * ac, MAX_SQDIST);
        float score = (1.0f - mink - a0 - p0) / (a0 * p0);
        float wgt = 1.0f / (1.0f + expf(score));        // sigmoid(-score)
        float minkn = dan - 2.0f * a0 * n0;
        float thn = fmaxf(-minkn, 1.0f + EPS);
        float acn = acoshf(thn);
        float neg_score = fminf(acn * acn, MAX_SQDIST);
        loss = fmaxf(pos_score - neg_score + MARGIN * wgt, 0.0f);
    }
    __shared__ float part[4];
    if (lane == 0) part[wib] = loss;
    __syncthreads();
    if (threadIdx.x == 0)
        partials[blockIdx.x] = part[0] + part[1] + part[2] + part[3];
}

// Final reduce. Single block, 1024 threads.
__global__ void reduce_kernel(const float* __restrict__ partials, float* __restrict__ out) {
    int tid = threadIdx.x;
    float s = 0.0f;
    for (int i = tid; i < LOSS_BLOCKS; i += 1024)
        s += partials[i];
    #pragma unroll
    for (int off = 32; off > 0; off >>= 1)
        s += __shfl_xor(s, off, 64);
    __shared__ float part[16];
    if ((tid & 63) == 0) part[tid >> 6] = s;
    __syncthreads();
    if (tid == 0) {
        float t = 0.0f;
        #pragma unroll
        for (int k = 0; k < 16; ++k) t += part[k];
        out[0] = t;
    }
}

extern "C" void kernel_launch(void* const* d_in, const int* in_sizes, int n_in,
                              void* d_out, int out_size, void* d_ws, size_t ws_size,
                              hipStream_t stream) {
    const float* weight   = (const float*)d_in[0];
    const float* adj_vals = (const float*)d_in[1];
    const int*   adj_row  = (const int*)d_in[2];
    const int*   adj_col  = (const int*)d_in[3];
    const int*   anchor   = (const int*)d_in[4];
    const int*   pos      = (const int*)d_in[5];
    const int*   neg      = (const int*)d_in[6];
    float* out = (float*)d_out;

    const size_t NODEF32 = (size_t)N_NODES * EMB_DIM * sizeof(float);           // 51.2 MB
    const size_t NODEBF  = (size_t)N_NODES * EMB_DIM * sizeof(unsigned short);  // 25.6 MB
    const size_t MB = 1024 * 1024;
    char* ws = (char*)d_ws;
    float* hfin = (float*)(ws);                        // final h (fp32)
    uint2* bf0  = (uint2*)(ws + NODEF32);              // x_t bf16
    uint2* bf1  = (uint2*)(ws + NODEF32 + NODEBF);     // h1 bf16
    uint2* bf2  = (uint2*)(ws + NODEF32 + 2 * NODEBF); // h2 bf16
    int*   rp   = (int*)  (ws + NODEF32 + 3 * NODEBF);            // row_ptr (800 KB)
    float* nrm2 = (float*)(ws + NODEF32 + 3 * NODEBF + 1 * MB);   // ||h||^2 (800 KB)
    int2*  ev   = (int2*) (ws + NODEF32 + 3 * NODEBF + 2 * MB);   // packed edges (12.8 MB)
    float* partials = (float*)(ws + NODEF32 + 3 * NODEBF + 16 * MB); // 64 KB

    prelude_kernel<<<PACK_BLOCKS + RP_BLOCKS + LOG_BLOCKS, 256, 0, stream>>>(
        adj_col, adj_vals, ev, adj_row, rp, weight, bf0);
    spmm_kernel<<<SPMM_BLOCKS, 256, 0, stream>>>(bf0, bf1, ev, rp);
    spmm_kernel<<<SPMM_BLOCKS, 256, 0, stream>>>(bf1, bf2, ev, rp);
    spmm_expmap_kernel<<<SPMM_BLOCKS, 256, 0, stream>>>(bf2, bf1, bf2, hfin, nrm2, ev, rp);
    loss_kernel<<<LOSS_BLOCKS, 256, 0, stream>>>(hfin, nrm2, anchor, pos, neg, partials);
    reduce_kernel<<<1, 1024, 0, stream>>>(partials, out);
}

// Round 10
// 333.694 us; speedup vs baseline: 1.3120x; 1.0585x over previous
//
#include <hip/hip_runtime.h>
#include <hip/hip_bf16.h>
#include <math.h>

#define N_NODES 200000
#define EMB_DIM 64
#define E_ADJ 1600000
#define E_TR 65536
#define NUM_NEG 16
#define EPS 1e-7f
#define MIN_NORM 1e-15f
#define MAX_SQDIST 50.0f
#define MARGIN 0.1f
#define LOSS_BLOCKS (E_TR / 4)     // 16384 blocks, 4 edges (waves) each
#define SPMM_BLOCKS 2048           // persistent: 8 blocks/CU x 256 CU
#define NWAVES (SPMM_BLOCKS * 4)   // 8192 waves
#define RPW 25                     // rows per wave (contiguous block)
#define LDS_CAP 512                // staged edges per wave (~200 expected)

#define PACK_BLOCKS ((E_ADJ + 255) / 256)        // 6250
#define RP_BLOCKS   ((N_NODES + 1 + 255) / 256)  // 782
#define LOG_BLOCKS  ((N_NODES + 15) / 16)        // 12500

typedef float f4 __attribute__((ext_vector_type(4)));

__device__ __forceinline__ float group_reduce16(float v) {
    v += __shfl_xor(v, 8, 64);
    v += __shfl_xor(v, 4, 64);
    v += __shfl_xor(v, 2, 64);
    v += __shfl_xor(v, 1, 64);
    return v;
}

__device__ __forceinline__ float dot4(f4 a, f4 b) {
    return a.x * b.x + a.y * b.y + a.z * b.z + a.w * b.w;
}

// ---- bf16 pack/unpack (RNE, unbiased) ----
__device__ __forceinline__ unsigned bfr(float f) {
    unsigned u = __float_as_uint(f);
    return (u + 0x7fffu + ((u >> 16) & 1u)) >> 16;
}
__device__ __forceinline__ uint2 f42bf(f4 v) {
    return make_uint2(bfr(v.x) | (bfr(v.y) << 16), bfr(v.z) | (bfr(v.w) << 16));
}
__device__ __forceinline__ f4 bf2f4(uint2 g) {
    f4 r;
    r.x = __uint_as_float(g.x << 16);
    r.y = __uint_as_float(g.x & 0xffff0000u);
    r.z = __uint_as_float(g.y << 16);
    r.w = __uint_as_float(g.y & 0xffff0000u);
    return r;
}

// Prelude: pack edges + row_ptr + logmap0, one dispatch (block-range split).
__global__ void prelude_kernel(const int* __restrict__ cols, const float* __restrict__ vals,
                               int2* __restrict__ ev, const int* __restrict__ rows,
                               int* __restrict__ rp, const float* __restrict__ w,
                               uint2* __restrict__ xt) {
    int b = blockIdx.x;
    if (b < PACK_BLOCKS) {
        int i = b * 256 + threadIdx.x;
        if (i < E_ADJ) ev[i] = make_int2(cols[i] << 4, __float_as_int(vals[i]));
    } else if (b < PACK_BLOCKS + RP_BLOCKS) {
        int r = (b - PACK_BLOCKS) * 256 + threadIdx.x;
        if (r <= N_NODES) {
            int lo = 0, hi = E_ADJ;
            while (lo < hi) {
                int mid = (lo + hi) >> 1;
                if (rows[mid] < r) lo = mid + 1; else hi = mid;
            }
            rp[r] = lo;
        }
    } else {
        int bb = b - PACK_BLOCKS - RP_BLOCKS;
        int wave = bb * 4 + (threadIdx.x >> 6);
        int lane = threadIdx.x & 63;
        int e = lane >> 4, d = lane & 15;
        int node = wave * 4 + e;
        if (node < N_NODES) {
            f4 v = ((const f4*)w)[(node << 4) + d];
            f4 y = v;
            if (d == 0) y.x = 0.0f;
            float n2 = group_reduce16(dot4(y, y));
            float ynorm = fmaxf(sqrtf(n2), MIN_NORM);
            float w0 = __shfl(v.x, lane & 48, 64);
            float theta = fmaxf(w0, 1.0f + EPS);
            float scale = acoshf(theta) / ynorm;
            xt[(node << 4) + d] = f42bf(y * scale);
        }
    }
}

// Per-group (16-lane) row accumulate: strict edge-index order, unroll x2.
// Group owns the whole 64-dim row (16 lanes x f4). No cross-group reduce.
__device__ __forceinline__ f4 row_accum(const uint2* __restrict__ h_in,
                                        const int2* __restrict__ ev,
                                        const int2* L, int ebase, int staged,
                                        int s, int e, int d) {
    f4 acc = {0.f, 0.f, 0.f, 0.f};
    int k = s;
    for (; k + 2 <= e; k += 2) {
        int o0 = k - ebase;
        int2 cv0, cv1;
        if (o0 + 1 < staged) { cv0 = L[o0]; cv1 = L[o0 + 1]; }
        else                 { cv0 = ev[k]; cv1 = ev[k + 1]; }
        uint2 g0 = h_in[cv0.x + d];
        uint2 g1 = h_in[cv1.x + d];
        acc += bf2f4(g0) * __int_as_float(cv0.y);
        acc += bf2f4(g1) * __int_as_float(cv1.y);
    }
    if (k < e) {
        int o = k - ebase;
        int2 cv;
        if (o < staged) cv = L[o]; else cv = ev[k];
        uint2 gg = h_in[cv.x + d];
        acc += bf2f4(gg) * __int_as_float(cv.y);
    }
    return acc;
}

// Kernel: persistent SpMM layer. Wave owns RPW contiguous rows; each 16-lane
// group processes one row independently (4 rows in flight, no per-row stall).
__global__ __launch_bounds__(256) void spmm_kernel(const uint2* __restrict__ h_in,
                                                   uint2* __restrict__ h_out,
                                                   const int2* __restrict__ ev,
                                                   const int* __restrict__ rp) {
    __shared__ int2 evs[4][LDS_CAP];               // 16 KB/block
    int wib = threadIdx.x >> 6;
    int lane = threadIdx.x & 63;
    int g = lane >> 4, d = lane & 15;
    int wid = __builtin_amdgcn_readfirstlane(blockIdx.x * 4 + wib);
    int r0 = wid * RPW;
    if (r0 >= N_NODES) return;                     // whole block exits together
    int r1 = min(r0 + RPW, N_NODES);
    int ebase = rp[r0];                            // s_load
    int etot  = rp[r1];
    int staged = min(etot - ebase, LDS_CAP);
    int2* L = evs[wib];
    for (int k = lane; k < staged; k += 64)        // coalesced bulk stage
        L[k] = ev[ebase + k];
    __syncthreads();

    for (int base = r0; base < r1; base += 4) {
        int row = base + g;
        bool valid = row < r1;
        int s = 0, e = 0;
        if (valid) { s = rp[row]; e = rp[row + 1]; }   // group-uniform vector loads
        f4 acc = row_accum(h_in, ev, L, ebase, staged, s, e, d);
        if (valid)
            h_out[(row << 4) + d] = f42bf(acc);    // 4 rows = 512 B contiguous/wave
    }
}

// Kernel: persistent fused layer-3 SpMM + (h1+h2+h3) + expmap0 + proj.
__global__ __launch_bounds__(256) void spmm_expmap_kernel(const uint2* __restrict__ h_gather,
                                                          const uint2* __restrict__ h1,
                                                          const uint2* __restrict__ h2,
                                                          float* __restrict__ h,
                                                          float* __restrict__ nrm2,
                                                          const int2* __restrict__ ev,
                                                          const int* __restrict__ rp) {
    __shared__ int2 evs[4][LDS_CAP];
    int wib = threadIdx.x >> 6;
    int lane = threadIdx.x & 63;
    int g = lane >> 4, d = lane & 15;
    int wid = __builtin_amdgcn_readfirstlane(blockIdx.x * 4 + wib);
    int r0 = wid * RPW;
    if (r0 >= N_NODES) return;
    int r1 = min(r0 + RPW, N_NODES);
    int ebase = rp[r0];
    int etot  = rp[r1];
    int staged = min(etot - ebase, LDS_CAP);
    int2* L = evs[wib];
    for (int k = lane; k < staged; k += 64)
        L[k] = ev[ebase + k];
    __syncthreads();

    for (int base = r0; base < r1; base += 4) {
        int row = base + g;
        bool valid = row < r1;
        int s = 0, e = 0;
        int oi = (row << 4) + d;
        f4 a1 = {0.f,0.f,0.f,0.f}, a2 = {0.f,0.f,0.f,0.f};
        if (valid) {
            s = rp[row]; e = rp[row + 1];
            a1 = bf2f4(h1[oi]);                    // issue early, overlap gathers
            a2 = bf2f4(h2[oi]);
        }
        f4 acc = row_accum(h_gather, ev, L, ebase, staged, s, e, d);
        if (valid) {
            f4 u = (a1 + a2) + acc;                // match ref accumulate order
            f4 x = u;
            if (d == 0) x.x = 0.0f;
            float n2 = group_reduce16(dot4(x, x)); // group-local: whole row in group
            float xn = fmaxf(sqrtf(n2), MIN_NORM);
            float sh = sinhf(xn);
            f4 rest = x * (sh / xn);
            float r2 = group_reduce16(dot4(rest, rest));
            float first = sqrtf(1.0f + r2);
            f4 ov = rest;
            if (d == 0) ov.x = first;
            ((f4*)h)[oi] = ov;
            if (d == 0) nrm2[row] = first * first + r2;
        }
    }
}

// Kernel: triplet loss + hard-negative mining. One wave per edge; lane=16e+d.
__global__ void loss_kernel(const float* __restrict__ h, const float* __restrict__ nrm2,
                            const int* __restrict__ anchor, const int* __restrict__ pos,
                            const int* __restrict__ neg, float* __restrict__ partials) {
    int wib = threadIdx.x >> 6;
    int lane = threadIdx.x & 63;
    int e = lane >> 4, d = lane & 15;
    int i = __builtin_amdgcn_readfirstlane(blockIdx.x * 4 + wib);
    const f4* H = (const f4*)h;

    int ia = anchor[i], ip = pos[i];               // s_load
    f4 a4 = H[(ia << 4) + d];
    f4 p4 = H[(ip << 4) + d];
    int4 nb4 = ((const int4*)(neg + (size_t)i * NUM_NEG))[e];  // group e: j = 4e+b

    float s[4];
    s[0] = dot4(p4, H[(nb4.x << 4) + d]);
    s[1] = dot4(p4, H[(nb4.y << 4) + d]);
    s[2] = dot4(p4, H[(nb4.z << 4) + d]);
    s[3] = dot4(p4, H[(nb4.w << 4) + d]);
    float dap = dot4(a4, p4);

    // reduce-scatter the 4 values across the 16-lane group
    {
        bool hi = (d & 8) != 0;
        float send0 = hi ? s[0] : s[2];
        float send1 = hi ? s[1] : s[3];
        float r0 = __shfl_xor(send0, 8, 64);
        float r1 = __shfl_xor(send1, 8, 64);
        float k0 = hi ? s[2] : s[0];
        float k1 = hi ? s[3] : s[1];
        s[0] = k0 + r0;
        s[1] = k1 + r1;
    }
    float sv;
    {
        bool hi = (d & 4) != 0;
        float send = hi ? s[0] : s[1];
        float r = __shfl_xor(send, 4, 64);
        float k = hi ? s[1] : s[0];
        sv = k + r;
    }
    sv += __shfl_xor(sv, 2, 64);
    sv += __shfl_xor(sv, 1, 64);
    // lane (e,d) holds <p,n_j> for j = 4e + b, b = ((d>>3)&1)*2 + ((d>>2)&1)
    int b_lane = ((d >> 3) & 1) * 2 + ((d >> 2) & 1);
    int nidx_lane = (d & 8) ? ((d & 4) ? nb4.w : nb4.z)
                            : ((d & 4) ? nb4.y : nb4.x);
    int j_lane = 4 * e + b_lane;

    float np2 = nrm2[ip];
    float bd = nrm2[nidx_lane] + np2 - 2.0f * sv;
    int bj = j_lane;
    // wave-wide argmin, first-occurrence tie-break (ties are duplicate nodes ->
    // bitwise-identical d2, so smaller-j rule matches jnp.argmin exactly)
    #pragma unroll
    for (int off = 32; off > 0; off >>= 1) {
        float od = __shfl_xor(bd, off, 64);
        int   oj = __shfl_xor(bj, off, 64);
        if (od < bd || (od == bd && oj < bj)) { bd = od; bj = oj; }
    }
    int bn = neg[(size_t)i * NUM_NEG + __builtin_amdgcn_readfirstlane(bj)];  // s_load
    f4 w4 = H[(bn << 4) + d];
    float dan = group_reduce16(dot4(a4, w4));
    dap = group_reduce16(dap);

    float loss = 0.0f;
    if (lane == 0) {
        float a0 = a4.x, p0 = p4.x, n0 = w4.x;
        float mink = dap - 2.0f * a0 * p0;
        float th = fmaxf(-mink, 1.0f + EPS);
        float ac = acoshf(th);
        float pos_score = fminf(ac * ac, MAX_SQDIST);
        float score = (1.0f - mink - a0 - p0) / (a0 * p0);
        float wgt = 1.0f / (1.0f + expf(score));        // sigmoid(-score)
        float minkn = dan - 2.0f * a0 * n0;
        float thn = fmaxf(-minkn, 1.0f + EPS);
        float acn = acoshf(thn);
        float neg_score = fminf(acn * acn, MAX_SQDIST);
        loss = fmaxf(pos_score - neg_score + MARGIN * wgt, 0.0f);
    }
    __shared__ float part[4];
    if (lane == 0) part[wib] = loss;
    __syncthreads();
    if (threadIdx.x == 0)
        partials[blockIdx.x] = part[0] + part[1] + part[2] + part[3];
}

// Final reduce. Single block, 1024 threads.
__global__ void reduce_kernel(const float* __restrict__ partials, float* __restrict__ out) {
    int tid = threadIdx.x;
    float s = 0.0f;
    for (int i = tid; i < LOSS_BLOCKS; i += 1024)
        s += partials[i];
    #pragma unroll
    for (int off = 32; off > 0; off >>= 1)
        s += __shfl_xor(s, off, 64);
    __shared__ float part[16];
    if ((tid & 63) == 0) part[tid >> 6] = s;
    __syncthreads();
    if (tid == 0) {
        float t = 0.0f;
        #pragma unroll
        for (int k = 0; k < 16; ++k) t += part[k];
        out[0] = t;
    }
}

extern "C" void kernel_launch(void* const* d_in, const int* in_sizes, int n_in,
                              void* d_out, int out_size, void* d_ws, size_t ws_size,
                              hipStream_t stream) {
    const float* weight   = (const float*)d_in[0];
    const float* adj_vals = (const float*)d_in[1];
    const int*   adj_row  = (const int*)d_in[2];
    const int*   adj_col  = (const int*)d_in[3];
    const int*   anchor   = (const int*)d_in[4];
    const int*   pos      = (const int*)d_in[5];
    const int*   neg      = (const int*)d_in[6];
    float* out = (float*)d_out;

    const size_t NODEF32 = (size_t)N_NODES * EMB_DIM * sizeof(float);           // 51.2 MB
    const size_t NODEBF  = (size_t)N_NODES * EMB_DIM * sizeof(unsigned short);  // 25.6 MB
    const size_t MB = 1024 * 1024;
    char* ws = (char*)d_ws;
    float* hfin = (float*)(ws);                        // final h (fp32)
    uint2* bf0  = (uint2*)(ws + NODEF32);              // x_t bf16
    uint2* bf1  = (uint2*)(ws + NODEF32 + NODEBF);     // h1 bf16
    uint2* bf2  = (uint2*)(ws + NODEF32 + 2 * NODEBF); // h2 bf16
    int*   rp   = (int*)  (ws + NODEF32 + 3 * NODEBF);            // row_ptr (800 KB)
    float* nrm2 = (float*)(ws + NODEF32 + 3 * NODEBF + 1 * MB);   // ||h||^2 (800 KB)
    int2*  ev   = (int2*) (ws + NODEF32 + 3 * NODEBF + 2 * MB);   // packed edges (12.8 MB)
    float* partials = (float*)(ws + NODEF32 + 3 * NODEBF + 16 * MB); // 64 KB

    prelude_kernel<<<PACK_BLOCKS + RP_BLOCKS + LOG_BLOCKS, 256, 0, stream>>>(
        adj_col, adj_vals, ev, adj_row, rp, weight, bf0);
    spmm_kernel<<<SPMM_BLOCKS, 256, 0, stream>>>(bf0, bf1, ev, rp);
    spmm_kernel<<<SPMM_BLOCKS, 256, 0, stream>>>(bf1, bf2, ev, rp);
    spmm_expmap_kernel<<<SPMM_BLOCKS, 256, 0, stream>>>(bf2, bf1, bf2, hfin, nrm2, ev, rp);
    loss_kernel<<<LOSS_BLOCKS, 256, 0, stream>>>(hfin, nrm2, anchor, pos, neg, partials);
    reduce_kernel<<<1, 1024, 0, stream>>>(partials, out);
}